// Round 1
// baseline (486.328 us; speedup 1.0000x reference)
//
#include <hip/hip_runtime.h>
#include <hip/hip_bf16.h>
#include <stdint.h>

#define N_ROWS 8192
#define DIN 2048
#define DOUT 2048
#define NE 8

#define BM 128
#define BN 128
#define BK 64
#define MAX_RT 71   // max total row-tiles: 8192/128 + (NE-1)

typedef __bf16 bf16x8 __attribute__((ext_vector_type(8)));
typedef float f32x4 __attribute__((ext_vector_type(4)));

__device__ __forceinline__ uint32_t f2bf(float f) {
  uint32_t u = __builtin_bit_cast(uint32_t, f);
  uint32_t r = u + 0x7FFFu + ((u >> 16) & 1u);   // RNE
  return r >> 16;
}

// ---------------- gating: prediction + argmax ----------------
__global__ __launch_bounds__(256) void gate_kernel(
    const float* __restrict__ cond, const float* __restrict__ Wp,
    const float* __restrict__ bp, int* __restrict__ idx, int* __restrict__ counts)
{
  __shared__ float wps[NE * DIN];          // 64 KB
  for (int i = threadIdx.x; i < NE * DIN / 4; i += 256)
    ((float4*)wps)[i] = ((const float4*)Wp)[i];
  __syncthreads();

  const int lane = threadIdx.x & 63;
  const int wid  = threadIdx.x >> 6;
  const int row  = blockIdx.x * 4 + wid;

  double acc[NE];
  #pragma unroll
  for (int e = 0; e < NE; ++e) acc[e] = 0.0;

  const float4* crow = (const float4*)(cond + (size_t)row * DIN);
  #pragma unroll
  for (int i = 0; i < DIN / 256; ++i) {    // 8 iters, 4 f32/lane each
    float4 c = crow[i * 64 + lane];
    #pragma unroll
    for (int e = 0; e < NE; ++e) {
      float4 w = ((const float4*)(wps + e * DIN))[i * 64 + lane];
      acc[e] += (double)c.x * w.x + (double)c.y * w.y
              + (double)c.z * w.z + (double)c.w * w.w;
    }
  }
  #pragma unroll
  for (int e = 0; e < NE; ++e) {
    double v = acc[e];
    #pragma unroll
    for (int off = 32; off > 0; off >>= 1) v += __shfl_down(v, off, 64);
    acc[e] = v;
  }
  if (lane == 0) {
    int best = 0; double bv = acc[0] + (double)bp[0];
    #pragma unroll
    for (int e = 1; e < NE; ++e) {
      double v = acc[e] + (double)bp[e];
      if (v > bv) { bv = v; best = e; }   // strict > keeps first index on tie (jnp.argmax)
    }
    idx[row] = best;
    atomicAdd(&counts[best], 1);
  }
}

// ---------------- tiny exclusive scan over 8 counts ----------------
__global__ void scan_kernel(const int* __restrict__ counts, int* __restrict__ offsets) {
  if (threadIdx.x == 0 && blockIdx.x == 0) {
    int s = 0;
    for (int e = 0; e < NE; ++e) { offsets[e] = s; s += counts[e]; }
  }
}

// ---------------- scatter rows into expert buckets ----------------
__global__ __launch_bounds__(256) void scatter_kernel(
    const int* __restrict__ idx, const int* __restrict__ offsets,
    int* __restrict__ fill, int* __restrict__ rows)
{
  int n = blockIdx.x * 256 + threadIdx.x;
  if (n >= N_ROWS) return;
  int e = idx[n];
  int pos = offsets[e] + atomicAdd(&fill[e], 1);
  rows[pos] = n;
}

// ---------------- grouped GEMM: out[row] = We[e] @ X[row] + be[e] ----------------
__global__ __launch_bounds__(256) void moe_gemm(
    const float* __restrict__ X, const float* __restrict__ We,
    const float* __restrict__ be, const int* __restrict__ counts,
    const int* __restrict__ offsets, const int* __restrict__ rows,
    float* __restrict__ out)
{
  __shared__ __align__(16) unsigned char Asb[BM * BK * 2];   // 16 KB bf16, XOR-swizzled
  __shared__ __align__(16) unsigned char Bsb[BN * BK * 2];   // 16 KB
  __shared__ int rowid[BM];

  const int ct = blockIdx.x;      // col tile (0..15)
  const int rt = blockIdx.y;      // global row tile

  // find which expert owns this row tile
  int e = 0, racc = 0, cnt = 0;
  for (; e < NE; ++e) {
    cnt = counts[e];
    int tiles = (cnt + BM - 1) / BM;
    if (rt < racc + tiles) break;
    racc += tiles;
  }
  if (e == NE) return;            // beyond last real tile
  const int row0 = (rt - racc) * BM;
  const int base = offsets[e];

  if (threadIdx.x < BM) {
    int r = row0 + threadIdx.x;
    rowid[threadIdx.x] = (r < cnt) ? rows[base + r] : -1;
  }
  __syncthreads();

  const int t    = threadIdx.x;
  const int lane = t & 63;
  const int wv   = t >> 6;          // wave 0..3
  const int wr   = wv >> 1, wc = wv & 1;
  const int g    = lane >> 4, fr = lane & 15;

  const int srow = t >> 4;          // staging: 0..15
  const int skq  = t & 15;          // float4 index within BK row

  f32x4 acc[4][4];
  #pragma unroll
  for (int m = 0; m < 4; ++m)
    #pragma unroll
    for (int n = 0; n < 4; ++n)
      acc[m][n] = 0.0f;

  const size_t bcol0 = (size_t)e * DOUT + (size_t)ct * BN;

  for (int k0 = 0; k0 < DIN; k0 += BK) {
    // ---- stage A (gathered rows, f32 -> bf16 RNE) ----
    #pragma unroll
    for (int p = 0; p < 8; ++p) {
      int r = p * 16 + srow;
      int gr = rowid[r];
      float4 v = make_float4(0.f, 0.f, 0.f, 0.f);
      if (gr >= 0)
        v = *(const float4*)(X + (size_t)gr * DIN + k0 + skq * 4);
      uint32_t w0 = f2bf(v.x) | (f2bf(v.y) << 16);
      uint32_t w1 = f2bf(v.z) | (f2bf(v.w) << 16);
      int byte = r * (BK * 2) + ((skq * 8) ^ ((r & 7) << 4));
      *(uint2*)(Asb + byte) = make_uint2(w0, w1);
    }
    // ---- stage B (We[e], N-major K-contiguous == B^T form) ----
    #pragma unroll
    for (int p = 0; p < 8; ++p) {
      int r = p * 16 + srow;
      float4 v = *(const float4*)(We + (bcol0 + r) * DIN + k0 + skq * 4);
      uint32_t w0 = f2bf(v.x) | (f2bf(v.y) << 16);
      uint32_t w1 = f2bf(v.z) | (f2bf(v.w) << 16);
      int byte = r * (BK * 2) + ((skq * 8) ^ ((r & 7) << 4));
      *(uint2*)(Bsb + byte) = make_uint2(w0, w1);
    }
    __syncthreads();

    #pragma unroll
    for (int kk = 0; kk < BK; kk += 32) {
      bf16x8 av[4], bv[4];
      #pragma unroll
      for (int m = 0; m < 4; ++m) {
        int r = wr * 64 + m * 16 + fr;
        int byte = r * (BK * 2) + ((((kk + g * 8) * 2)) ^ ((r & 7) << 4));
        av[m] = *(const bf16x8*)(Asb + byte);
      }
      #pragma unroll
      for (int n = 0; n < 4; ++n) {
        int c = wc * 64 + n * 16 + fr;
        int byte = c * (BK * 2) + ((((kk + g * 8) * 2)) ^ ((c & 7) << 4));
        bv[n] = *(const bf16x8*)(Bsb + byte);
      }
      #pragma unroll
      for (int m = 0; m < 4; ++m)
        #pragma unroll
        for (int n = 0; n < 4; ++n)
          acc[m][n] = __builtin_amdgcn_mfma_f32_16x16x32_bf16(av[m], bv[n], acc[m][n], 0, 0, 0);
    }
    __syncthreads();
  }

  // ---- epilogue: add bias, scatter rows back ----
  const float* berow = be + (size_t)e * DOUT + (size_t)ct * BN + wc * 64;
  #pragma unroll
  for (int m = 0; m < 4; ++m) {
    #pragma unroll
    for (int j = 0; j < 4; ++j) {
      int r = wr * 64 + m * 16 + g * 4 + j;
      int grow = rowid[r];
      if (grow < 0) continue;
      float* orow = out + (size_t)grow * DOUT + (size_t)ct * BN + wc * 64;
      #pragma unroll
      for (int n = 0; n < 4; ++n)
        orow[n * 16 + fr] = acc[m][n][j] + berow[n * 16 + fr];
    }
  }
}

extern "C" void kernel_launch(void* const* d_in, const int* in_sizes, int n_in,
                              void* d_out, int out_size, void* d_ws, size_t ws_size,
                              hipStream_t stream) {
  const float* X    = (const float*)d_in[0];
  const float* cond = (const float*)d_in[1];
  const float* Wp   = (const float*)d_in[2];
  const float* bp   = (const float*)d_in[3];
  const float* We   = (const float*)d_in[4];
  const float* be   = (const float*)d_in[5];
  float* out = (float*)d_out;

  int* counts  = (int*)d_ws;            // [8]
  int* offsets = counts + 8;            // [8]
  int* fill    = counts + 16;           // [8]
  int* idx     = (int*)((char*)d_ws + 256);   // [N]
  int* rows    = idx + N_ROWS;                // [N]

  hipMemsetAsync(d_ws, 0, 256, stream);
  gate_kernel<<<N_ROWS / 4, 256, 0, stream>>>(cond, Wp, bp, idx, counts);
  scan_kernel<<<1, 64, 0, stream>>>(counts, offsets);
  scatter_kernel<<<N_ROWS / 256, 256, 0, stream>>>(idx, offsets, fill, rows);
  moe_gemm<<<dim3(DOUT / BN, MAX_RT), 256, 0, stream>>>(X, We, be, counts, offsets, rows, out);
}

// Round 2
// 367.019 us; speedup vs baseline: 1.3251x; 1.3251x over previous
//
#include <hip/hip_runtime.h>
#include <hip/hip_bf16.h>
#include <stdint.h>

#define N_ROWS 8192
#define DIN 2048
#define DOUT 2048
#define NE 8

#define BM 128
#define BN 128
#define BK 64
#define MAX_RT 71   // max total row-tiles: 8192/128 + (NE-1)

typedef __bf16 bf16x8 __attribute__((ext_vector_type(8)));
typedef float f32x4 __attribute__((ext_vector_type(4)));

__device__ __forceinline__ uint32_t f2bf(float f) {
  uint32_t u = __builtin_bit_cast(uint32_t, f);
  uint32_t r = u + 0x7FFFu + ((u >> 16) & 1u);   // RNE
  return r >> 16;
}

__device__ __forceinline__ void gl2lds16(const void* g, void* l) {
  __builtin_amdgcn_global_load_lds(
      (const __attribute__((address_space(1))) unsigned int*)g,
      (__attribute__((address_space(3))) unsigned int*)l, 16, 0, 0);
}

// ---------------- gating: prediction + argmax (no LDS; Wp is L2-hot) ----------------
__global__ __launch_bounds__(256) void gate_kernel(
    const float* __restrict__ cond, const float* __restrict__ Wp,
    const float* __restrict__ bp, int* __restrict__ idx, int* __restrict__ counts)
{
  const int lane = threadIdx.x & 63;
  const int wid  = threadIdx.x >> 6;
  const int row  = blockIdx.x * 4 + wid;

  double acc[NE];
  #pragma unroll
  for (int e = 0; e < NE; ++e) acc[e] = 0.0;

  const float4* crow = (const float4*)(cond + (size_t)row * DIN);
  const float4* wp4  = (const float4*)Wp;
  #pragma unroll
  for (int i = 0; i < DIN / 256; ++i) {    // 8 iters, 4 f32/lane each
    float4 c = crow[i * 64 + lane];
    #pragma unroll
    for (int e = 0; e < NE; ++e) {
      float4 w = wp4[e * (DIN / 4) + i * 64 + lane];
      acc[e] += (double)c.x * w.x + (double)c.y * w.y
              + (double)c.z * w.z + (double)c.w * w.w;
    }
  }
  #pragma unroll
  for (int e = 0; e < NE; ++e) {
    double v = acc[e];
    #pragma unroll
    for (int off = 32; off > 0; off >>= 1) v += __shfl_down(v, off, 64);
    acc[e] = v;
  }
  if (lane == 0) {
    int best = 0; double bv = acc[0] + (double)bp[0];
    #pragma unroll
    for (int e = 1; e < NE; ++e) {
      double v = acc[e] + (double)bp[e];
      if (v > bv) { bv = v; best = e; }   // strict > keeps first index on tie
    }
    idx[row] = best;
    atomicAdd(&counts[best], 1);
  }
}

// ---------------- tiny exclusive scan over 8 counts ----------------
__global__ void scan_kernel(const int* __restrict__ counts, int* __restrict__ offsets) {
  if (threadIdx.x == 0 && blockIdx.x == 0) {
    int s = 0;
    for (int e = 0; e < NE; ++e) { offsets[e] = s; s += counts[e]; }
  }
}

// ---------------- scatter rows into expert buckets ----------------
__global__ __launch_bounds__(256) void scatter_kernel(
    const int* __restrict__ idx, const int* __restrict__ offsets,
    int* __restrict__ fill, int* __restrict__ rows)
{
  int n = blockIdx.x * 256 + threadIdx.x;
  if (n >= N_ROWS) return;
  int e = idx[n];
  int pos = offsets[e] + atomicAdd(&fill[e], 1);
  rows[pos] = n;
}

// ---------------- permute + convert X into bucket order (f32 -> bf16) ----------------
__global__ __launch_bounds__(256) void permute_kernel(
    const float* __restrict__ X, const int* __restrict__ rows,
    __hip_bfloat16* __restrict__ Xp)
{
  const int lane = threadIdx.x & 63;
  const int wv   = threadIdx.x >> 6;
  const int p    = blockIdx.x * 4 + wv;        // dest slot
  const int src  = rows[p];
  const float4* s = (const float4*)(X + (size_t)src * DIN);
  uint2* d = (uint2*)(Xp + (size_t)p * DIN);
  #pragma unroll
  for (int c = 0; c < DIN / 256; ++c) {
    float4 v = s[c * 64 + lane];
    uint32_t w0 = f2bf(v.x) | (f2bf(v.y) << 16);
    uint32_t w1 = f2bf(v.z) | (f2bf(v.w) << 16);
    d[c * 64 + lane] = make_uint2(w0, w1);
  }
}

// ---------------- convert We f32 -> bf16 ----------------
__global__ __launch_bounds__(256) void convWe_kernel(
    const float* __restrict__ We, __hip_bfloat16* __restrict__ Web)
{
  const size_t total = (size_t)NE * DOUT * DIN / 8;   // chunks of 8 elems
  const size_t stride = (size_t)gridDim.x * 256;
  for (size_t c = (size_t)blockIdx.x * 256 + threadIdx.x; c < total; c += stride) {
    float4 v0 = ((const float4*)We)[c * 2];
    float4 v1 = ((const float4*)We)[c * 2 + 1];
    uint4 o;
    o.x = f2bf(v0.x) | (f2bf(v0.y) << 16);
    o.y = f2bf(v0.z) | (f2bf(v0.w) << 16);
    o.z = f2bf(v1.x) | (f2bf(v1.y) << 16);
    o.w = f2bf(v1.z) | (f2bf(v1.w) << 16);
    ((uint4*)Web)[c] = o;
  }
}

// ---------------- grouped GEMM, m97 structure: global_load_lds + linear LDS ----------------
__global__ __launch_bounds__(256) void moe_gemm2(
    const __hip_bfloat16* __restrict__ Xp, const __hip_bfloat16* __restrict__ Web,
    const float* __restrict__ be, const int* __restrict__ counts,
    const int* __restrict__ offsets, const int* __restrict__ rows,
    float* __restrict__ out)
{
  __shared__ __align__(16) __hip_bfloat16 As[BM * BK];   // 16 KB linear
  __shared__ __align__(16) __hip_bfloat16 Bs[BN * BK];   // 16 KB linear
  __shared__ int rowid[BM];

  const int ct = blockIdx.x;      // col tile (0..15)
  const int rt = blockIdx.y;      // global row tile

  int e = 0, racc = 0, cnt = 0;
  for (; e < NE; ++e) {
    cnt = counts[e];
    int tiles = (cnt + BM - 1) / BM;
    if (rt < racc + tiles) break;
    racc += tiles;
  }
  if (e == NE) return;
  const int row0 = (rt - racc) * BM;
  const int base = offsets[e];
  const int t = threadIdx.x;

  if (t < BM)
    rowid[t] = (row0 + t < cnt) ? rows[base + row0 + t] : -1;

  const int lane = t & 63;
  const int wv   = t >> 6;
  const int wr   = wv >> 1, wc = wv & 1;
  const int g    = lane >> 4, fr = lane & 15;

  f32x4 acc[4][4];
  #pragma unroll
  for (int m = 0; m < 4; ++m)
    #pragma unroll
    for (int n = 0; n < 4; ++n)
      acc[m][n] = 0.0f;

  // staging addressing: thread t covers row (p*32 + t>>3), 16B chunk (t&7) of BK row
  const int srow = t >> 3;                 // 0..31
  const int scol = (t & 7) * 8;            // bf16 elems
  const size_t rowbase = (size_t)(base + row0);
  const size_t bcol = (size_t)e * DOUT + (size_t)ct * BN;

  const __hip_bfloat16* aSrc = Xp + (rowbase + srow) * DIN + scol;
  const __hip_bfloat16* bSrc = Web + (bcol + srow) * DIN + scol;
  char* aDst = (char*)As + t * 16;         // == wave base + lane*16, linear
  char* bDst = (char*)Bs + t * 16;

  for (int k0 = 0; k0 < DIN; k0 += BK) {
    #pragma unroll
    for (int p = 0; p < 4; ++p)
      gl2lds16(aSrc + (size_t)p * 32 * DIN + k0, aDst + p * 4096);
    #pragma unroll
    for (int p = 0; p < 4; ++p)
      gl2lds16(bSrc + (size_t)p * 32 * DIN + k0, bDst + p * 4096);
    __syncthreads();

    #pragma unroll
    for (int kk = 0; kk < BK; kk += 32) {
      bf16x8 av[4], bv[4];
      #pragma unroll
      for (int m = 0; m < 4; ++m)
        av[m] = *(const bf16x8*)((const char*)As + (wr * 64 + m * 16 + fr) * (BK * 2) + (kk + g * 8) * 2);
      #pragma unroll
      for (int n = 0; n < 4; ++n)
        bv[n] = *(const bf16x8*)((const char*)Bs + (wc * 64 + n * 16 + fr) * (BK * 2) + (kk + g * 8) * 2);
      #pragma unroll
      for (int m = 0; m < 4; ++m)
        #pragma unroll
        for (int n = 0; n < 4; ++n)
          acc[m][n] = __builtin_amdgcn_mfma_f32_16x16x32_bf16(av[m], bv[n], acc[m][n], 0, 0, 0);
    }
    __syncthreads();
  }

  const float* berow = be + (size_t)e * DOUT + (size_t)ct * BN + wc * 64;
  #pragma unroll
  for (int m = 0; m < 4; ++m) {
    #pragma unroll
    for (int j = 0; j < 4; ++j) {
      int r = wr * 64 + m * 16 + g * 4 + j;
      int grow = rowid[r];
      if (grow < 0) continue;
      float* orow = out + (size_t)grow * DOUT + (size_t)ct * BN + wc * 64;
      #pragma unroll
      for (int n = 0; n < 4; ++n)
        orow[n * 16 + fr] = acc[m][n][j] + berow[n * 16 + fr];
    }
  }
}

// ---------------- fallback grouped GEMM (round-1, reg-staged f32) ----------------
__global__ __launch_bounds__(256) void moe_gemm_fb(
    const float* __restrict__ X, const float* __restrict__ We,
    const float* __restrict__ be, const int* __restrict__ counts,
    const int* __restrict__ offsets, const int* __restrict__ rows,
    float* __restrict__ out)
{
  __shared__ __align__(16) unsigned char Asb[BM * BK * 2];
  __shared__ __align__(16) unsigned char Bsb[BN * BK * 2];
  __shared__ int rowid[BM];

  const int ct = blockIdx.x;
  const int rt = blockIdx.y;

  int e = 0, racc = 0, cnt = 0;
  for (; e < NE; ++e) {
    cnt = counts[e];
    int tiles = (cnt + BM - 1) / BM;
    if (rt < racc + tiles) break;
    racc += tiles;
  }
  if (e == NE) return;
  const int row0 = (rt - racc) * BM;
  const int base = offsets[e];

  if (threadIdx.x < BM) {
    int r = row0 + threadIdx.x;
    rowid[threadIdx.x] = (r < cnt) ? rows[base + r] : -1;
  }
  __syncthreads();

  const int t    = threadIdx.x;
  const int lane = t & 63;
  const int wv   = t >> 6;
  const int wr   = wv >> 1, wc = wv & 1;
  const int g    = lane >> 4, fr = lane & 15;
  const int srow = t >> 4;
  const int skq  = t & 15;

  f32x4 acc[4][4];
  #pragma unroll
  for (int m = 0; m < 4; ++m)
    #pragma unroll
    for (int n = 0; n < 4; ++n)
      acc[m][n] = 0.0f;

  const size_t bcol0 = (size_t)e * DOUT + (size_t)ct * BN;

  for (int k0 = 0; k0 < DIN; k0 += BK) {
    #pragma unroll
    for (int p = 0; p < 8; ++p) {
      int r = p * 16 + srow;
      int gr = rowid[r];
      float4 v = make_float4(0.f, 0.f, 0.f, 0.f);
      if (gr >= 0)
        v = *(const float4*)(X + (size_t)gr * DIN + k0 + skq * 4);
      uint32_t w0 = f2bf(v.x) | (f2bf(v.y) << 16);
      uint32_t w1 = f2bf(v.z) | (f2bf(v.w) << 16);
      int byte = r * (BK * 2) + ((skq * 8) ^ ((r & 7) << 4));
      *(uint2*)(Asb + byte) = make_uint2(w0, w1);
    }
    #pragma unroll
    for (int p = 0; p < 8; ++p) {
      int r = p * 16 + srow;
      float4 v = *(const float4*)(We + (bcol0 + r) * DIN + k0 + skq * 4);
      uint32_t w0 = f2bf(v.x) | (f2bf(v.y) << 16);
      uint32_t w1 = f2bf(v.z) | (f2bf(v.w) << 16);
      int byte = r * (BK * 2) + ((skq * 8) ^ ((r & 7) << 4));
      *(uint2*)(Bsb + byte) = make_uint2(w0, w1);
    }
    __syncthreads();

    #pragma unroll
    for (int kk = 0; kk < BK; kk += 32) {
      bf16x8 av[4], bv[4];
      #pragma unroll
      for (int m = 0; m < 4; ++m) {
        int r = wr * 64 + m * 16 + fr;
        int byte = r * (BK * 2) + ((((kk + g * 8) * 2)) ^ ((r & 7) << 4));
        av[m] = *(const bf16x8*)(Asb + byte);
      }
      #pragma unroll
      for (int n = 0; n < 4; ++n) {
        int c = wc * 64 + n * 16 + fr;
        int byte = c * (BK * 2) + ((((kk + g * 8) * 2)) ^ ((c & 7) << 4));
        bv[n] = *(const bf16x8*)(Bsb + byte);
      }
      #pragma unroll
      for (int m = 0; m < 4; ++m)
        #pragma unroll
        for (int n = 0; n < 4; ++n)
          acc[m][n] = __builtin_amdgcn_mfma_f32_16x16x32_bf16(av[m], bv[n], acc[m][n], 0, 0, 0);
    }
    __syncthreads();
  }

  const float* berow = be + (size_t)e * DOUT + (size_t)ct * BN + wc * 64;
  #pragma unroll
  for (int m = 0; m < 4; ++m) {
    #pragma unroll
    for (int j = 0; j < 4; ++j) {
      int r = wr * 64 + m * 16 + g * 4 + j;
      int grow = rowid[r];
      if (grow < 0) continue;
      float* orow = out + (size_t)grow * DOUT + (size_t)ct * BN + wc * 64;
      #pragma unroll
      for (int n = 0; n < 4; ++n)
        orow[n * 16 + fr] = acc[m][n][j] + berow[n * 16 + fr];
    }
  }
}

extern "C" void kernel_launch(void* const* d_in, const int* in_sizes, int n_in,
                              void* d_out, int out_size, void* d_ws, size_t ws_size,
                              hipStream_t stream) {
  const float* X    = (const float*)d_in[0];
  const float* cond = (const float*)d_in[1];
  const float* Wp   = (const float*)d_in[2];
  const float* bp   = (const float*)d_in[3];
  const float* We   = (const float*)d_in[4];
  const float* be   = (const float*)d_in[5];
  float* out = (float*)d_out;

  // ws layout
  int* counts  = (int*)d_ws;                       // [8]   @0
  int* offsets = counts + 8;                       // [8]   @32
  int* fill    = counts + 16;                      // [8]   @64
  int* idx     = (int*)((char*)d_ws + 256);        // [8192]
  int* rows    = idx + N_ROWS;                     // [8192] ends @65792
  const size_t XP_OFF  = 65792;
  const size_t XP_ROWS = N_ROWS + BM;              // pad for tile overrun reads
  const size_t WEB_OFF = XP_OFF + XP_ROWS * DIN * 2;           // 34,144,512
  const size_t WS_NEED = WEB_OFF + (size_t)NE * DOUT * DIN * 2; // ~101.3 MB

  hipMemsetAsync(d_ws, 0, 256, stream);
  gate_kernel<<<N_ROWS / 4, 256, 0, stream>>>(cond, Wp, bp, idx, counts);
  scan_kernel<<<1, 64, 0, stream>>>(counts, offsets);
  scatter_kernel<<<N_ROWS / 256, 256, 0, stream>>>(idx, offsets, fill, rows);

  if (ws_size >= WS_NEED) {
    __hip_bfloat16* Xp  = (__hip_bfloat16*)((char*)d_ws + XP_OFF);
    __hip_bfloat16* Web = (__hip_bfloat16*)((char*)d_ws + WEB_OFF);
    permute_kernel<<<N_ROWS / 4, 256, 0, stream>>>(X, rows, Xp);
    convWe_kernel<<<4096, 256, 0, stream>>>(We, Web);
    moe_gemm2<<<dim3(DOUT / BN, MAX_RT), 256, 0, stream>>>(Xp, Web, be, counts, offsets, rows, out);
  } else {
    moe_gemm_fb<<<dim3(DOUT / BN, MAX_RT), 256, 0, stream>>>(X, We, be, counts, offsets, rows, out);
  }
}

// Round 3
// 225.860 us; speedup vs baseline: 2.1532x; 1.6250x over previous
//
#include <hip/hip_runtime.h>
#include <hip/hip_bf16.h>
#include <stdint.h>

#define N_ROWS 8192
#define DIN 2048
#define DOUT 2048
#define NE 8

#define BM 128
#define BN 128
#define BK 64
#define MAX_RT 71   // max total row-tiles: 8192/128 + (NE-1)

typedef __bf16 bf16x8 __attribute__((ext_vector_type(8)));
typedef float f32x4 __attribute__((ext_vector_type(4)));

__device__ __forceinline__ uint32_t f2bf(float f) {
  uint32_t u = __builtin_bit_cast(uint32_t, f);
  uint32_t r = u + 0x7FFFu + ((u >> 16) & 1u);   // RNE
  return r >> 16;
}

__device__ __forceinline__ void gl2lds16(const void* g, void* l) {
  __builtin_amdgcn_global_load_lds(
      (const __attribute__((address_space(1))) unsigned int*)g,
      (__attribute__((address_space(3))) unsigned int*)l, 16, 0, 0);
}

// ---------------- gating: prediction + argmax (math identical to passing rounds) ----------------
__global__ __launch_bounds__(256) void gate_kernel(
    const float* __restrict__ cond, const float* __restrict__ Wp,
    const float* __restrict__ bp, int* __restrict__ idx)
{
  const int lane = threadIdx.x & 63;
  const int wid  = threadIdx.x >> 6;
  const int row  = blockIdx.x * 4 + wid;

  double acc[NE];
  #pragma unroll
  for (int e = 0; e < NE; ++e) acc[e] = 0.0;

  const float4* crow = (const float4*)(cond + (size_t)row * DIN);
  const float4* wp4  = (const float4*)Wp;
  #pragma unroll
  for (int i = 0; i < DIN / 256; ++i) {
    float4 c = crow[i * 64 + lane];
    #pragma unroll
    for (int e = 0; e < NE; ++e) {
      float4 w = wp4[e * (DIN / 4) + i * 64 + lane];
      acc[e] += (double)c.x * w.x + (double)c.y * w.y
              + (double)c.z * w.z + (double)c.w * w.w;
    }
  }
  #pragma unroll
  for (int e = 0; e < NE; ++e) {
    double v = acc[e];
    #pragma unroll
    for (int off = 32; off > 0; off >>= 1) v += __shfl_down(v, off, 64);
    acc[e] = v;
  }
  if (lane == 0) {
    int best = 0; double bv = acc[0] + (double)bp[0];
    #pragma unroll
    for (int e = 1; e < NE; ++e) {
      double v = acc[e] + (double)bp[e];
      if (v > bv) { bv = v; best = e; }
    }
    idx[row] = best;
  }
}

// ---------------- block-aggregated histogram ----------------
__global__ __launch_bounds__(256) void hist_kernel(
    const int* __restrict__ idx, int* __restrict__ counts)
{
  __shared__ int lc[NE];
  const int t = threadIdx.x;
  if (t < NE) lc[t] = 0;
  __syncthreads();
  int n = blockIdx.x * 256 + t;
  atomicAdd(&lc[idx[n]], 1);
  __syncthreads();
  if (t < NE && lc[t] > 0) atomicAdd(&counts[t], lc[t]);
}

// ---------------- tiny exclusive scan over 8 counts ----------------
__global__ void scan_kernel(const int* __restrict__ counts, int* __restrict__ offsets) {
  if (threadIdx.x == 0 && blockIdx.x == 0) {
    int s = 0;
    for (int e = 0; e < NE; ++e) { offsets[e] = s; s += counts[e]; }
  }
}

// ---------------- block-aggregated scatter ----------------
__global__ __launch_bounds__(256) void scatter_kernel(
    const int* __restrict__ idx, const int* __restrict__ offsets,
    int* __restrict__ fill, int* __restrict__ rows)
{
  __shared__ int lc[NE], lb[NE];
  const int t = threadIdx.x;
  if (t < NE) lc[t] = 0;
  __syncthreads();
  int n = blockIdx.x * 256 + t;
  int e = idx[n];
  int my = atomicAdd(&lc[e], 1);
  __syncthreads();
  if (t < NE) lb[t] = (lc[t] > 0) ? atomicAdd(&fill[t], lc[t]) : 0;
  __syncthreads();
  rows[offsets[e] + lb[e] + my] = n;
}

// ---------------- streaming f32 -> bf16 conversion ----------------
__global__ __launch_bounds__(256) void conv_kernel(
    const float* __restrict__ src, __hip_bfloat16* __restrict__ dst, size_t nchunks)
{
  const size_t stride = (size_t)gridDim.x * 256;
  for (size_t c = (size_t)blockIdx.x * 256 + threadIdx.x; c < nchunks; c += stride) {
    float4 v0 = ((const float4*)src)[c * 2];
    float4 v1 = ((const float4*)src)[c * 2 + 1];
    uint4 o;
    o.x = f2bf(v0.x) | (f2bf(v0.y) << 16);
    o.y = f2bf(v0.z) | (f2bf(v0.w) << 16);
    o.z = f2bf(v1.x) | (f2bf(v1.y) << 16);
    o.w = f2bf(v1.z) | (f2bf(v1.w) << 16);
    ((uint4*)dst)[c] = o;
  }
}

// ---------------- grouped GEMM: 128^2, double-buffered 2-phase, gathered A ----------------
__global__ __launch_bounds__(256) void moe_gemm3(
    const __hip_bfloat16* __restrict__ Xb, const __hip_bfloat16* __restrict__ Web,
    const float* __restrict__ be, const int* __restrict__ counts,
    const int* __restrict__ offsets, const int* __restrict__ rows,
    float* __restrict__ out)
{
  __shared__ __align__(16) __hip_bfloat16 As[2][BM * BK];   // 2 x 16 KB
  __shared__ __align__(16) __hip_bfloat16 Bs[2][BN * BK];   // 2 x 16 KB
  __shared__ int rowid[BM];

  const int ct = blockIdx.x;      // col tile (0..15)
  const int rt = blockIdx.y;      // global row tile

  int e = 0, racc = 0, cnt = 0;
  for (; e < NE; ++e) {
    cnt = counts[e];
    int tiles = (cnt + BM - 1) / BM;
    if (rt < racc + tiles) break;
    racc += tiles;
  }
  if (e == NE) return;
  const int row0 = (rt - racc) * BM;
  const int base = offsets[e];
  const int t = threadIdx.x;

  if (t < BM)
    rowid[t] = (row0 + t < cnt) ? rows[base + row0 + t] : -1;
  __syncthreads();

  // gathered A source pointers: chunk c = p*256+t covers row c>>3, 16B piece c&7
  const __hip_bfloat16* aSrcP[4];
  #pragma unroll
  for (int p = 0; p < 4; ++p) {
    int c = p * 256 + t;
    int gr = rowid[c >> 3];
    if (gr < 0) gr = 0;                       // safe row; results for pad rows discarded
    aSrcP[p] = Xb + (size_t)gr * DIN + (c & 7) * 8;
  }
  const size_t bcol0 = (size_t)e * DOUT + (size_t)ct * BN;
  const __hip_bfloat16* bSrc0 = Web + (bcol0 + (t >> 3)) * DIN + (t & 7) * 8;

  const int lane = t & 63;
  const int wv   = t >> 6;
  const int wr   = wv >> 1, wc = wv & 1;
  const int g    = lane >> 4, fr = lane & 15;

  f32x4 acc[4][4];
  #pragma unroll
  for (int m = 0; m < 4; ++m)
    #pragma unroll
    for (int n = 0; n < 4; ++n)
      acc[m][n] = 0.0f;

#define STAGE(buf, k0) do {                                                     \
    _Pragma("unroll")                                                           \
    for (int p = 0; p < 4; ++p) {                                               \
      gl2lds16(aSrcP[p] + (k0), (char*)As[buf] + p * 4096 + t * 16);            \
      gl2lds16(bSrc0 + (size_t)p * 32 * DIN + (k0),                             \
               (char*)Bs[buf] + p * 4096 + t * 16);                             \
    } } while (0)

#define COMPUTE(buf) do {                                                       \
    _Pragma("unroll")                                                           \
    for (int kk = 0; kk < BK; kk += 32) {                                       \
      bf16x8 av[4], bv[4];                                                      \
      _Pragma("unroll")                                                         \
      for (int m = 0; m < 4; ++m)                                               \
        av[m] = *(const bf16x8*)((const char*)As[buf] +                         \
                 (wr * 64 + m * 16 + fr) * (BK * 2) + (kk + g * 8) * 2);        \
      _Pragma("unroll")                                                         \
      for (int n = 0; n < 4; ++n)                                               \
        bv[n] = *(const bf16x8*)((const char*)Bs[buf] +                         \
                 (wc * 64 + n * 16 + fr) * (BK * 2) + (kk + g * 8) * 2);        \
      __builtin_amdgcn_s_setprio(1);                                            \
      _Pragma("unroll")                                                         \
      for (int m = 0; m < 4; ++m)                                               \
        _Pragma("unroll")                                                       \
        for (int n = 0; n < 4; ++n)                                             \
          acc[m][n] = __builtin_amdgcn_mfma_f32_16x16x32_bf16(av[m], bv[n],     \
                                                              acc[m][n], 0,0,0);\
      __builtin_amdgcn_s_setprio(0);                                            \
    } } while (0)

  STAGE(0, 0);
  __syncthreads();
  int k0 = BK;
  #pragma unroll 1
  for (int it = 0; it < 15; ++it) {
    STAGE(1, k0); COMPUTE(0); __syncthreads(); k0 += BK;
    STAGE(0, k0); COMPUTE(1); __syncthreads(); k0 += BK;
  }
  STAGE(1, k0); COMPUTE(0); __syncthreads();   // k0 == 1984
  COMPUTE(1);

#undef STAGE
#undef COMPUTE

  const float* berow = be + (size_t)e * DOUT + (size_t)ct * BN + wc * 64;
  #pragma unroll
  for (int m = 0; m < 4; ++m) {
    #pragma unroll
    for (int j = 0; j < 4; ++j) {
      int r = wr * 64 + m * 16 + g * 4 + j;
      int grow = rowid[r];
      if (grow < 0) continue;
      float* orow = out + (size_t)grow * DOUT + (size_t)ct * BN + wc * 64;
      #pragma unroll
      for (int n = 0; n < 4; ++n)
        orow[n * 16 + fr] = acc[m][n][j] + berow[n * 16 + fr];
    }
  }
}

// ---------------- fallback grouped GEMM (reg-staged f32, known-good) ----------------
__global__ __launch_bounds__(256) void moe_gemm_fb(
    const float* __restrict__ X, const float* __restrict__ We,
    const float* __restrict__ be, const int* __restrict__ counts,
    const int* __restrict__ offsets, const int* __restrict__ rows,
    float* __restrict__ out)
{
  __shared__ __align__(16) unsigned char Asb[BM * BK * 2];
  __shared__ __align__(16) unsigned char Bsb[BN * BK * 2];
  __shared__ int rowid[BM];

  const int ct = blockIdx.x;
  const int rt = blockIdx.y;

  int e = 0, racc = 0, cnt = 0;
  for (; e < NE; ++e) {
    cnt = counts[e];
    int tiles = (cnt + BM - 1) / BM;
    if (rt < racc + tiles) break;
    racc += tiles;
  }
  if (e == NE) return;
  const int row0 = (rt - racc) * BM;
  const int base = offsets[e];

  if (threadIdx.x < BM) {
    int r = row0 + threadIdx.x;
    rowid[threadIdx.x] = (r < cnt) ? rows[base + r] : -1;
  }
  __syncthreads();

  const int t    = threadIdx.x;
  const int lane = t & 63;
  const int wv   = t >> 6;
  const int wr   = wv >> 1, wc = wv & 1;
  const int g    = lane >> 4, fr = lane & 15;
  const int srow = t >> 4;
  const int skq  = t & 15;

  f32x4 acc[4][4];
  #pragma unroll
  for (int m = 0; m < 4; ++m)
    #pragma unroll
    for (int n = 0; n < 4; ++n)
      acc[m][n] = 0.0f;

  const size_t bcol0 = (size_t)e * DOUT + (size_t)ct * BN;

  for (int k0 = 0; k0 < DIN; k0 += BK) {
    #pragma unroll
    for (int p = 0; p < 8; ++p) {
      int r = p * 16 + srow;
      int gr = rowid[r];
      float4 v = make_float4(0.f, 0.f, 0.f, 0.f);
      if (gr >= 0)
        v = *(const float4*)(X + (size_t)gr * DIN + k0 + skq * 4);
      uint32_t w0 = f2bf(v.x) | (f2bf(v.y) << 16);
      uint32_t w1 = f2bf(v.z) | (f2bf(v.w) << 16);
      int byte = r * (BK * 2) + ((skq * 8) ^ ((r & 7) << 4));
      *(uint2*)(Asb + byte) = make_uint2(w0, w1);
    }
    #pragma unroll
    for (int p = 0; p < 8; ++p) {
      int r = p * 16 + srow;
      float4 v = *(const float4*)(We + (bcol0 + r) * DIN + k0 + skq * 4);
      uint32_t w0 = f2bf(v.x) | (f2bf(v.y) << 16);
      uint32_t w1 = f2bf(v.z) | (f2bf(v.w) << 16);
      int byte = r * (BK * 2) + ((skq * 8) ^ ((r & 7) << 4));
      *(uint2*)(Bsb + byte) = make_uint2(w0, w1);
    }
    __syncthreads();

    #pragma unroll
    for (int kk = 0; kk < BK; kk += 32) {
      bf16x8 av[4], bv[4];
      #pragma unroll
      for (int m = 0; m < 4; ++m) {
        int r = wr * 64 + m * 16 + fr;
        int byte = r * (BK * 2) + ((((kk + g * 8) * 2)) ^ ((r & 7) << 4));
        av[m] = *(const bf16x8*)(Asb + byte);
      }
      #pragma unroll
      for (int n = 0; n < 4; ++n) {
        int c = wc * 64 + n * 16 + fr;
        int byte = c * (BK * 2) + ((((kk + g * 8) * 2)) ^ ((c & 7) << 4));
        bv[n] = *(const bf16x8*)(Bsb + byte);
      }
      #pragma unroll
      for (int m = 0; m < 4; ++m)
        #pragma unroll
        for (int n = 0; n < 4; ++n)
          acc[m][n] = __builtin_amdgcn_mfma_f32_16x16x32_bf16(av[m], bv[n], acc[m][n], 0, 0, 0);
    }
    __syncthreads();
  }

  const float* berow = be + (size_t)e * DOUT + (size_t)ct * BN + wc * 64;
  #pragma unroll
  for (int m = 0; m < 4; ++m) {
    #pragma unroll
    for (int j = 0; j < 4; ++j) {
      int r = wr * 64 + m * 16 + g * 4 + j;
      int grow = rowid[r];
      if (grow < 0) continue;
      float* orow = out + (size_t)grow * DOUT + (size_t)ct * BN + wc * 64;
      #pragma unroll
      for (int n = 0; n < 4; ++n)
        orow[n * 16 + fr] = acc[m][n][j] + berow[n * 16 + fr];
    }
  }
}

extern "C" void kernel_launch(void* const* d_in, const int* in_sizes, int n_in,
                              void* d_out, int out_size, void* d_ws, size_t ws_size,
                              hipStream_t stream) {
  const float* X    = (const float*)d_in[0];
  const float* cond = (const float*)d_in[1];
  const float* Wp   = (const float*)d_in[2];
  const float* bp   = (const float*)d_in[3];
  const float* We   = (const float*)d_in[4];
  const float* be   = (const float*)d_in[5];
  float* out = (float*)d_out;

  // ws layout
  int* counts  = (int*)d_ws;                       // [8]
  int* offsets = counts + 8;                       // [8]
  int* fill    = counts + 16;                      // [8]
  int* idx     = (int*)((char*)d_ws + 256);        // [8192]
  int* rows    = idx + N_ROWS;                     // [8192]
  const size_t XB_OFF  = 65792;                    // 256-aligned
  const size_t WEB_OFF = XB_OFF + (size_t)N_ROWS * DIN * 2;       // +32 MB
  const size_t WS_NEED = WEB_OFF + (size_t)NE * DOUT * DIN * 2;   // ~96 MB

  hipMemsetAsync(d_ws, 0, 256, stream);
  gate_kernel<<<N_ROWS / 4, 256, 0, stream>>>(cond, Wp, bp, idx);
  hist_kernel<<<N_ROWS / 256, 256, 0, stream>>>(idx, counts);
  scan_kernel<<<1, 64, 0, stream>>>(counts, offsets);
  scatter_kernel<<<N_ROWS / 256, 256, 0, stream>>>(idx, offsets, fill, rows);

  if (ws_size >= WS_NEED) {
    __hip_bfloat16* Xb  = (__hip_bfloat16*)((char*)d_ws + XB_OFF);
    __hip_bfloat16* Web = (__hip_bfloat16*)((char*)d_ws + WEB_OFF);
    conv_kernel<<<2048, 256, 0, stream>>>(X, Xb, (size_t)N_ROWS * DIN / 8);
    conv_kernel<<<2048, 256, 0, stream>>>(We, Web, (size_t)NE * DOUT * DIN / 8);
    moe_gemm3<<<dim3(DOUT / BN, MAX_RT), 256, 0, stream>>>(Xb, Web, be, counts, offsets, rows, out);
  } else {
    moe_gemm_fb<<<dim3(DOUT / BN, MAX_RT), 256, 0, stream>>>(X, We, be, counts, offsets, rows, out);
  }
}